// Round 4
// baseline (225.284 us; speedup 1.0000x reference)
//
#include <hip/hip_runtime.h>
#include <math.h>

namespace {
constexpr int Mz = 256, Lz = 24, Sz = 22, Bz = 4;
constexpr int Wz = Mz + Lz - 1;        // 279
constexpr int HST = 22;                 // Hs/Ys stride: 8B-aligned rows, min bank aliasing
constexpr int XST = 25;                 // xs stride: odd -> conflict-free
constexpr int NBLK = Bz * Mz;           // 1024
constexpr double SIGM_DEN = (double)Mz * (double)Wz * (double)Bz * 1e4;
}

__device__ __forceinline__ unsigned int enc_f32(float f) {
  unsigned int u = __float_as_uint(f);
  return (u & 0x80000000u) ? ~u : (u | 0x80000000u);
}
__device__ __forceinline__ float dec_f32(unsigned int e) {
  unsigned int u = (e & 0x80000000u) ? (e ^ 0x80000000u) : ~e;
  return __uint_as_float(u);
}

// Zero reduction scalars + barrier; hsum[m*256+n] = sum_s H2[m,n,s].
__global__ __launch_bounds__(256) void k_init(const float* __restrict__ H,
                                              float* __restrict__ hsum,
                                              double* __restrict__ sumsq,
                                              unsigned int* __restrict__ maxenc,
                                              unsigned int* __restrict__ bar)
{
  int idx = blockIdx.x * 256 + threadIdx.x;
  if (idx == 0) { *sumsq = 0.0; *maxenc = 0u; *bar = 0u; }
  if (idx < Mz * Mz) {
    const float2* __restrict__ hp = (const float2*)(H + (size_t)idx * Sz);
    float a = 0.f;
    #pragma unroll
    for (int k = 0; k < 11; ++k) { float2 h = hp[k]; a += h.x + h.y; }
    hsum[idx] = a;
  }
}

// One block per (b,m): Y0 in LDS, sum(Y0^2) accumulated, X0 written to d_out.
__global__ __launch_bounds__(512, 4) void k_fwd(const float* __restrict__ x,
                                                const float* __restrict__ H,
                                                float* __restrict__ X0,
                                                double* __restrict__ sumsq)
{
  __shared__ __align__(16) float Hs[Mz * HST];   // 22528 B (exact copy of H slab)
  __shared__ __align__(16) float Ys[Wz * HST];   // 24552 B
  __shared__ __align__(16) float xs[Mz * XST];   // 25600 B (padded rows)
  __shared__ double wred[8];

  const int tid = threadIdx.x;
  const int b = blockIdx.x >> 8;
  const int m = blockIdx.x & 255;
  const float* __restrict__ xp = x + (size_t)(b * Mz + m) * (Mz * Lz);
  const float* __restrict__ Hp = H + (size_t)m * (Mz * Sz);

  // ---- stage Hs (contiguous float4 copy) ----
  {
    const float4* __restrict__ src = (const float4*)Hp;
    float4* dst = (float4*)Hs;
    #pragma unroll 3
    for (int e = tid; e < Mz * HST / 4; e += 512) dst[e] = src[e];
  }
  // ---- stage xs (float4 global read, padded scalar LDS writes; 4|24 so no row cross) ----
  #pragma unroll 3
  for (int e = tid; e < Mz * Lz / 4; e += 512) {
    float4 v = ((const float4*)xp)[e];
    int j = 4 * e, r = j / 24, c = j - r * 24;
    float* d = &xs[r * XST + c];
    d[0] = v.x; d[1] = v.y; d[2] = v.z; d[3] = v.w;
  }
  __syncthreads();

  // ---- Y0[w,s] = sum_i Hs[w-i][s] * xs[w-i][i]; thread owns one w ----
  double local = 0.0;
  for (int w = tid; w < Wz; w += 512) {
    const int i0 = (w > Mz - 1) ? (w - (Mz - 1)) : 0;
    const int i1 = (w < Lz - 1) ? w : (Lz - 1);
    float2 acc[11];
    #pragma unroll
    for (int k = 0; k < 11; ++k) acc[k] = make_float2(0.f, 0.f);
    for (int i = i0; i <= i1; ++i) {
      const int n = w - i;
      const float xv = xs[n * XST + i];
      const float2* __restrict__ hrow = (const float2*)&Hs[n * HST];
      #pragma unroll
      for (int k = 0; k < 11; ++k) {
        float2 h = hrow[k];
        acc[k].x = fmaf(h.x, xv, acc[k].x);
        acc[k].y = fmaf(h.y, xv, acc[k].y);
      }
    }
    float2* yrow = (float2*)&Ys[w * HST];
    #pragma unroll
    for (int k = 0; k < 11; ++k) {
      yrow[k] = acc[k];
      local += (double)acc[k].x * acc[k].x + (double)acc[k].y * acc[k].y;
    }
  }

  // ---- block-reduce sumsq (also serves as the Ys barrier) ----
  for (int off = 32; off > 0; off >>= 1) local += __shfl_down(local, off, 64);
  const int lane = tid & 63, wid = tid >> 6;
  if (lane == 0) wred[wid] = local;
  __syncthreads();
  if (tid == 0) {
    double s = 0.0;
    #pragma unroll
    for (int k = 0; k < 8; ++k) s += wred[k];
    atomicAdd(sumsq, s);
  }

  // ---- X0[n,l] = sum_s Ys[n+l][s]*Hs[n][s]; thread owns (n = tid/2, 12 l's) ----
  {
    const int n = tid >> 1;
    const int l0 = (tid & 1) * 12;
    const float2* __restrict__ hr2 = (const float2*)&Hs[n * HST];
    float hr[22];
    #pragma unroll
    for (int k = 0; k < 11; ++k) { float2 h = hr2[k]; hr[2*k] = h.x; hr[2*k+1] = h.y; }
    float outv[12];
    #pragma unroll
    for (int j = 0; j < 12; ++j) {
      const float2* __restrict__ yr = (const float2*)&Ys[(n + l0 + j) * HST];
      float a0 = 0.f, a1 = 0.f;
      #pragma unroll
      for (int k = 0; k < 11; ++k) {
        float2 y = yr[k];
        a0 = fmaf(y.x, hr[2*k],   a0);
        a1 = fmaf(y.y, hr[2*k+1], a1);
      }
      outv[j] = a0 + a1;
    }
    float4* __restrict__ Xp4 =
        (float4*)(X0 + (size_t)(b * Mz + m) * (Mz * Lz) + tid * 12);
    Xp4[0] = make_float4(outv[0], outv[1], outv[2],  outv[3]);
    Xp4[1] = make_float4(outv[4], outv[5], outv[6],  outv[7]);
    Xp4[2] = make_float4(outv[8], outv[9], outv[10], outv[11]);
  }
}

// Fused: v = X0 + c*eps*hsum (regs), global max via atomic + spin barrier, scale, store.
// One block per (b,m); thread n owns row n (24 l's). Grid 1024 == resident capacity.
__global__ __launch_bounds__(256, 4) void k_maxfinal(float* __restrict__ Xio,
                                                     const float* __restrict__ eps,
                                                     const float* __restrict__ hsum,
                                                     const double* __restrict__ sumsq,
                                                     unsigned int* __restrict__ maxenc,
                                                     unsigned int* __restrict__ bar)
{
  const float c = sqrtf((float)(*sumsq / SIGM_DEN));
  const int n = threadIdx.x;
  const int bm = blockIdx.x;
  const int m = bm & 255;
  float* __restrict__ row = Xio + (size_t)bm * (Mz * Lz) + n * Lz;
  const float* __restrict__ ep = eps + bm * Wz + n;
  const float hv = c * hsum[(m << 8) + n];

  float v[24];
  {
    const float4* __restrict__ r4 = (const float4*)row;
    #pragma unroll
    for (int q = 0; q < 6; ++q) {
      float4 t = r4[q];
      v[4*q+0] = t.x; v[4*q+1] = t.y; v[4*q+2] = t.z; v[4*q+3] = t.w;
    }
  }
  float mx = -3.4e38f;
  #pragma unroll
  for (int l = 0; l < 24; ++l) {
    v[l] = fmaf(hv, ep[l], v[l]);
    mx = fmaxf(mx, v[l]);
  }

  // block max -> device max -> spin barrier
  for (int off = 32; off > 0; off >>= 1) mx = fmaxf(mx, __shfl_down(mx, off, 64));
  __shared__ float wredf[4];
  __shared__ unsigned int smax;
  const int lane = n & 63, wid = n >> 6;
  if (lane == 0) wredf[wid] = mx;
  __syncthreads();
  if (n == 0) {
    float bmx = fmaxf(fmaxf(wredf[0], wredf[1]), fmaxf(wredf[2], wredf[3]));
    atomicMax(maxenc, enc_f32(bmx));
    __threadfence();
    __hip_atomic_fetch_add(bar, 1u, __ATOMIC_ACQ_REL, __HIP_MEMORY_SCOPE_AGENT);
    while (__hip_atomic_load(bar, __ATOMIC_ACQUIRE, __HIP_MEMORY_SCOPE_AGENT) < (unsigned)NBLK) {}
    smax = __hip_atomic_load(maxenc, __ATOMIC_ACQUIRE, __HIP_MEMORY_SCOPE_AGENT);
  }
  __syncthreads();

  const float inv = 1.0f / dec_f32(smax);
  float4* __restrict__ w4 = (float4*)row;
  #pragma unroll
  for (int q = 0; q < 6; ++q)
    w4[q] = make_float4(v[4*q+0]*inv, v[4*q+1]*inv, v[4*q+2]*inv, v[4*q+3]*inv);
}

extern "C" void kernel_launch(void* const* d_in, const int* in_sizes, int n_in,
                              void* d_out, int out_size, void* d_ws, size_t ws_size,
                              hipStream_t stream) {
  const float* x   = (const float*)d_in[0];   // (4,256,256,24)
  const float* H   = (const float*)d_in[1];   // (1,256,256,1,22)
  const float* eps = (const float*)d_in[2];   // (4,256,279,1)
  float* out = (float*)d_out;                 // (4,256,256,24)

  double*       sumsq  = (double*)d_ws;
  unsigned int* maxenc = (unsigned int*)((char*)d_ws + 8);
  unsigned int* bar    = (unsigned int*)((char*)d_ws + 12);
  float*        hsum   = (float*)((char*)d_ws + 16);   // 256KB

  k_init     <<<(Mz * Mz + 255) / 256, 256, 0, stream>>>(H, hsum, sumsq, maxenc, bar);
  k_fwd      <<<NBLK, 512, 0, stream>>>(x, H, out, sumsq);
  k_maxfinal <<<NBLK, 256, 0, stream>>>(out, eps, hsum, sumsq, maxenc, bar);
}

// Round 6
// 137.873 us; speedup vs baseline: 1.6340x; 1.6340x over previous
//
#include <hip/hip_runtime.h>
#include <math.h>

namespace {
constexpr int Mz = 256, Lz = 24, Sz = 22, Bz = 4;
constexpr int Wz = Mz + Lz - 1;        // 279
constexpr int ST = 23;                  // Hs/Ys stride: odd -> 2-way max (free)
constexpr int XST = 25;                 // xs stride: odd -> conflict-free
constexpr int NBLK = Bz * Mz;           // 1024
constexpr double SIGM_DEN = (double)Mz * (double)Wz * (double)Bz * 1e4;
}

__device__ __forceinline__ unsigned int enc_f32(float f) {
  unsigned int u = __float_as_uint(f);
  return (u & 0x80000000u) ? ~u : (u | 0x80000000u);
}
__device__ __forceinline__ float dec_f32(unsigned int e) {
  unsigned int u = (e & 0x80000000u) ? (e ^ 0x80000000u) : ~e;
  return __uint_as_float(u);
}

// Zero reduction scalars; hsum[m*256+n] = sum_s H2[m,n,s].
__global__ __launch_bounds__(256) void k_init(const float* __restrict__ H,
                                              float* __restrict__ hsum,
                                              double* __restrict__ sumsq,
                                              unsigned int* __restrict__ maxenc)
{
  int idx = blockIdx.x * 256 + threadIdx.x;
  if (idx == 0) { *sumsq = 0.0; *maxenc = 0u; }
  if (idx < Mz * Mz) {
    const float* __restrict__ hp = H + (size_t)idx * Sz;
    float a = 0.f;
    #pragma unroll
    for (int s = 0; s < Sz; ++s) a += hp[s];
    hsum[idx] = a;
  }
}

// One block per (b,m): Y0 in LDS, sum(Y0^2) accumulated, X0 written to d_out.
// Structure identical to the measured 53us version except: xs stride 25
// (was 24: 16-way conflict) and register-tiled X0 phase (thread owns row n).
__global__ __launch_bounds__(256) void k_fwd(const float* __restrict__ x,
                                             const float* __restrict__ H,
                                             float* __restrict__ X0,
                                             double* __restrict__ sumsq)
{
  __shared__ float Hs[Mz * ST];    // 23552 B
  __shared__ float Ys[Wz * ST];    // 25668 B
  __shared__ float xs[Mz * XST];   // 25600 B
  __shared__ double wred[4];

  const int tid = threadIdx.x;
  const int b = blockIdx.x >> 8;
  const int m = blockIdx.x & 255;
  const float* __restrict__ xp = x + (size_t)(b * Mz + m) * (Mz * Lz);
  const float* __restrict__ Hp = H + (size_t)m * (Mz * Sz);

  // ---- stage Hs (coalesced global read, padded LDS store) ----
  for (int e = tid; e < Mz * Sz; e += 256) {
    int n = e / Sz, s = e - n * Sz;
    Hs[n * ST + s] = Hp[e];
  }
  // ---- stage xs (coalesced global read, padded LDS store) ----
  for (int e = tid; e < Mz * Lz; e += 256) {
    int n = e / Lz, i = e - n * Lz;
    xs[n * XST + i] = xp[e];
  }
  __syncthreads();

  // ---- Y0[w,s] = sum_i Hs[w-i][s] * xs[w-i][i]; thread owns one w ----
  double local = 0.0;
  for (int w = tid; w < Wz; w += 256) {
    const int i0 = (w > Mz - 1) ? (w - (Mz - 1)) : 0;
    const int i1 = (w < Lz - 1) ? w : (Lz - 1);
    float acc[Sz];
    #pragma unroll
    for (int s = 0; s < Sz; ++s) acc[s] = 0.f;
    for (int i = i0; i <= i1; ++i) {
      const int n = w - i;
      const float xv = xs[n * XST + i];
      const float* __restrict__ hrow = &Hs[n * ST];
      #pragma unroll
      for (int s = 0; s < Sz; ++s) acc[s] = fmaf(hrow[s], xv, acc[s]);
    }
    float* __restrict__ yrow = &Ys[w * ST];
    #pragma unroll
    for (int s = 0; s < Sz; ++s) {
      yrow[s] = acc[s];
      local += (double)acc[s] * (double)acc[s];
    }
  }

  // ---- block-reduce sumsq (syncthreads also publishes Ys) ----
  for (int off = 32; off > 0; off >>= 1) local += __shfl_down(local, off, 64);
  const int lane = tid & 63, wid = tid >> 6;
  if (lane == 0) wred[wid] = local;
  __syncthreads();
  if (tid == 0) atomicAdd(sumsq, wred[0] + wred[1] + wred[2] + wred[3]);

  // ---- X0[n,l] = sum_s Ys[n+l][s]*Hs[n][s]; thread owns row n, H[n] in regs ----
  {
    const int n = tid;
    float hr[Sz];
    const float* __restrict__ hrow = &Hs[n * ST];
    #pragma unroll
    for (int s = 0; s < Sz; ++s) hr[s] = hrow[s];

    float4* __restrict__ Xp4 =
        (float4*)(X0 + (size_t)(b * Mz + m) * (Mz * Lz) + n * Lz);
    #pragma unroll
    for (int q = 0; q < 6; ++q) {
      float o[4];
      #pragma unroll
      for (int j = 0; j < 4; ++j) {
        const int l = 4 * q + j;
        const float* __restrict__ yr = &Ys[(n + l) * ST];
        float a = 0.f;
        #pragma unroll
        for (int s = 0; s < Sz; ++s) a = fmaf(yr[s], hr[s], a);
        o[j] = a;
      }
      Xp4[q] = make_float4(o[0], o[1], o[2], o[3]);
    }
  }
}

// One block per (b,m); thread n owns row n: max of X0 + c*eps*hsum.
__global__ __launch_bounds__(256) void k_max(const float* __restrict__ X0,
                                             const float* __restrict__ eps,
                                             const float* __restrict__ hsum,
                                             const double* __restrict__ sumsq,
                                             unsigned int* __restrict__ maxenc)
{
  const float c = sqrtf((float)(*sumsq / SIGM_DEN));
  const int n = threadIdx.x;
  const int bm = blockIdx.x;
  const int m = bm & 255;
  const float4* __restrict__ r4 = (const float4*)(X0 + (size_t)bm * (Mz * Lz) + n * Lz);
  const float* __restrict__ ep = eps + bm * Wz + n;
  const float hv = c * hsum[(m << 8) + n];

  float mx = -3.4e38f;
  #pragma unroll
  for (int q = 0; q < 6; ++q) {
    float4 t = r4[q];
    mx = fmaxf(mx, fmaf(hv, ep[4*q+0], t.x));
    mx = fmaxf(mx, fmaf(hv, ep[4*q+1], t.y));
    mx = fmaxf(mx, fmaf(hv, ep[4*q+2], t.z));
    mx = fmaxf(mx, fmaf(hv, ep[4*q+3], t.w));
  }
  for (int off = 32; off > 0; off >>= 1) mx = fmaxf(mx, __shfl_down(mx, off, 64));
  __shared__ float wredf[4];
  const int lane = n & 63, wid = n >> 6;
  if (lane == 0) wredf[wid] = mx;
  __syncthreads();
  if (n == 0) {
    float bmx = fmaxf(fmaxf(wredf[0], wredf[1]), fmaxf(wredf[2], wredf[3]));
    atomicMax(maxenc, enc_f32(bmx));
  }
}

// One block per (b,m); thread n owns row n: out = (X0 + c*eps*hsum)/max.
__global__ __launch_bounds__(256) void k_final(float* __restrict__ Xio,
                                               const float* __restrict__ eps,
                                               const float* __restrict__ hsum,
                                               const double* __restrict__ sumsq,
                                               const unsigned int* __restrict__ maxenc)
{
  const float c = sqrtf((float)(*sumsq / SIGM_DEN));
  const float inv = 1.0f / dec_f32(*maxenc);
  const int n = threadIdx.x;
  const int bm = blockIdx.x;
  const int m = bm & 255;
  float4* __restrict__ r4 = (float4*)(Xio + (size_t)bm * (Mz * Lz) + n * Lz);
  const float* __restrict__ ep = eps + bm * Wz + n;
  const float hv = c * hsum[(m << 8) + n];

  #pragma unroll
  for (int q = 0; q < 6; ++q) {
    float4 t = r4[q];
    t.x = fmaf(hv, ep[4*q+0], t.x) * inv;
    t.y = fmaf(hv, ep[4*q+1], t.y) * inv;
    t.z = fmaf(hv, ep[4*q+2], t.z) * inv;
    t.w = fmaf(hv, ep[4*q+3], t.w) * inv;
    r4[q] = t;
  }
}

extern "C" void kernel_launch(void* const* d_in, const int* in_sizes, int n_in,
                              void* d_out, int out_size, void* d_ws, size_t ws_size,
                              hipStream_t stream) {
  const float* x   = (const float*)d_in[0];   // (4,256,256,24)
  const float* H   = (const float*)d_in[1];   // (1,256,256,1,22)
  const float* eps = (const float*)d_in[2];   // (4,256,279,1)
  float* out = (float*)d_out;                 // (4,256,256,24)

  double*       sumsq  = (double*)d_ws;
  unsigned int* maxenc = (unsigned int*)((char*)d_ws + 8);
  float*        hsum   = (float*)((char*)d_ws + 16);   // 256KB

  k_init  <<<(Mz * Mz + 255) / 256, 256, 0, stream>>>(H, hsum, sumsq, maxenc);
  k_fwd   <<<NBLK, 256, 0, stream>>>(x, H, out, sumsq);
  k_max   <<<NBLK, 256, 0, stream>>>(out, eps, hsum, sumsq, maxenc);
  k_final <<<NBLK, 256, 0, stream>>>(out, eps, hsum, sumsq, maxenc);
}

// Round 7
// 135.949 us; speedup vs baseline: 1.6571x; 1.0142x over previous
//
#include <hip/hip_runtime.h>
#include <math.h>

namespace {
constexpr int Mz = 256, Lz = 24, Sz = 22, Bz = 4;
constexpr int Wz = Mz + Lz - 1;        // 279
constexpr int ST = 26;                  // Hs/Ys float2 stride: 26n mod 32 distinct over n mod 16 -> b64 conflict-free
constexpr int XT = 257;                 // xs^T stride: reads are consecutive-addr, writes (257c+r) conflict-free
constexpr int NBLK = Bz * Mz;           // 1024
constexpr double SIGM_DEN = (double)Mz * (double)Wz * (double)Bz * 1e4;
}

__device__ __forceinline__ unsigned int enc_f32(float f) {
  unsigned int u = __float_as_uint(f);
  return (u & 0x80000000u) ? ~u : (u | 0x80000000u);
}
__device__ __forceinline__ float dec_f32(unsigned int e) {
  unsigned int u = (e & 0x80000000u) ? (e ^ 0x80000000u) : ~e;
  return __uint_as_float(u);
}

// Zero reduction scalars; hsum[m*256+n] = sum_s H2[m,n,s].
__global__ __launch_bounds__(256) void k_init(const float* __restrict__ H,
                                              float* __restrict__ hsum,
                                              double* __restrict__ sumsq,
                                              unsigned int* __restrict__ maxenc)
{
  int idx = blockIdx.x * 256 + threadIdx.x;
  if (idx == 0) { *sumsq = 0.0; *maxenc = 0u; }
  if (idx < Mz * Mz) {
    const float* __restrict__ hp = H + (size_t)idx * Sz;
    float a = 0.f;
    #pragma unroll
    for (int s = 0; s < Sz; ++s) a += hp[s];
    hsum[idx] = a;
  }
}

// One block per (b,m): Y0 in LDS, sum(Y0^2) accumulated, X0 written to d_out.
// Delta vs measured round-6 k_fwd: Hs/Ys stride 26 + float2 (b64) LDS ops,
// xs stored transposed [i][n] stride 257. Everything else identical.
__global__ __launch_bounds__(256) void k_fwd(const float* __restrict__ x,
                                             const float* __restrict__ H,
                                             float* __restrict__ X0,
                                             double* __restrict__ sumsq)
{
  __shared__ __align__(16) float Hs[Mz * ST];    // 26624 B
  __shared__ __align__(16) float Ys[Wz * ST];    // 29016 B
  __shared__ __align__(16) float xs[Lz * XT];    // 24672 B  (xs[i*XT+n] = x[n][i])
  __shared__ double wred[4];

  const int tid = threadIdx.x;
  const int b = blockIdx.x >> 8;
  const int m = blockIdx.x & 255;
  const float* __restrict__ xp = x + (size_t)(b * Mz + m) * (Mz * Lz);
  const float* __restrict__ Hp = H + (size_t)m * (Mz * Sz);

  // ---- stage Hs (coalesced global read, padded LDS store) ----
  for (int e = tid; e < Mz * Sz; e += 256) {
    int n = e / Sz, s = e - n * Sz;
    Hs[n * ST + s] = Hp[e];
  }
  // ---- stage xs transposed (coalesced global read; write banks (257c+r)%32 spread) ----
  for (int e = tid; e < Mz * Lz; e += 256) {
    int n = e / Lz, i = e - n * Lz;
    xs[i * XT + n] = xp[e];
  }
  __syncthreads();

  // ---- Y0[w,s] = sum_i Hs[w-i][s] * x[w-i][i]; thread owns one w ----
  double local = 0.0;
  for (int w = tid; w < Wz; w += 256) {
    const int i0 = (w > Mz - 1) ? (w - (Mz - 1)) : 0;
    const int i1 = (w < Lz - 1) ? w : (Lz - 1);
    float2 acc[11];
    #pragma unroll
    for (int k = 0; k < 11; ++k) acc[k] = make_float2(0.f, 0.f);
    for (int i = i0; i <= i1; ++i) {
      const int n = w - i;
      const float xv = xs[i * XT + n];
      const float2* __restrict__ hrow = (const float2*)&Hs[n * ST];
      #pragma unroll
      for (int k = 0; k < 11; ++k) {
        const float2 h = hrow[k];
        acc[k].x = fmaf(h.x, xv, acc[k].x);
        acc[k].y = fmaf(h.y, xv, acc[k].y);
      }
    }
    float2* __restrict__ yrow = (float2*)&Ys[w * ST];
    #pragma unroll
    for (int k = 0; k < 11; ++k) {
      yrow[k] = acc[k];
      local += (double)acc[k].x * acc[k].x + (double)acc[k].y * acc[k].y;
    }
  }

  // ---- block-reduce sumsq (syncthreads also publishes Ys) ----
  for (int off = 32; off > 0; off >>= 1) local += __shfl_down(local, off, 64);
  const int lane = tid & 63, wid = tid >> 6;
  if (lane == 0) wred[wid] = local;
  __syncthreads();
  if (tid == 0) atomicAdd(sumsq, wred[0] + wred[1] + wred[2] + wred[3]);

  // ---- X0[n,l] = sum_s Ys[n+l][s]*Hs[n][s]; thread owns row n, H[n] in regs ----
  {
    const int n = tid;
    float hr[Sz];
    {
      const float2* __restrict__ h2 = (const float2*)&Hs[n * ST];
      #pragma unroll
      for (int k = 0; k < 11; ++k) { const float2 h = h2[k]; hr[2*k] = h.x; hr[2*k+1] = h.y; }
    }
    float4* __restrict__ Xp4 =
        (float4*)(X0 + (size_t)(b * Mz + m) * (Mz * Lz) + n * Lz);
    #pragma unroll
    for (int q = 0; q < 6; ++q) {
      float o[4];
      #pragma unroll
      for (int j = 0; j < 4; ++j) {
        const int l = 4 * q + j;
        const float2* __restrict__ yr = (const float2*)&Ys[(n + l) * ST];
        float a0 = 0.f, a1 = 0.f;
        #pragma unroll
        for (int k = 0; k < 11; ++k) {
          const float2 y = yr[k];
          a0 = fmaf(y.x, hr[2*k],   a0);
          a1 = fmaf(y.y, hr[2*k+1], a1);
        }
        o[j] = a0 + a1;
      }
      Xp4[q] = make_float4(o[0], o[1], o[2], o[3]);
    }
  }
}

// One block per (b,m); thread n owns row n: max of X0 + c*eps*hsum.
__global__ __launch_bounds__(256) void k_max(const float* __restrict__ X0,
                                             const float* __restrict__ eps,
                                             const float* __restrict__ hsum,
                                             const double* __restrict__ sumsq,
                                             unsigned int* __restrict__ maxenc)
{
  const float c = sqrtf((float)(*sumsq / SIGM_DEN));
  const int n = threadIdx.x;
  const int bm = blockIdx.x;
  const int m = bm & 255;
  const float4* __restrict__ r4 = (const float4*)(X0 + (size_t)bm * (Mz * Lz) + n * Lz);
  const float* __restrict__ ep = eps + bm * Wz + n;
  const float hv = c * hsum[(m << 8) + n];

  float mx = -3.4e38f;
  #pragma unroll
  for (int q = 0; q < 6; ++q) {
    float4 t = r4[q];
    mx = fmaxf(mx, fmaf(hv, ep[4*q+0], t.x));
    mx = fmaxf(mx, fmaf(hv, ep[4*q+1], t.y));
    mx = fmaxf(mx, fmaf(hv, ep[4*q+2], t.z));
    mx = fmaxf(mx, fmaf(hv, ep[4*q+3], t.w));
  }
  for (int off = 32; off > 0; off >>= 1) mx = fmaxf(mx, __shfl_down(mx, off, 64));
  __shared__ float wredf[4];
  const int lane = n & 63, wid = n >> 6;
  if (lane == 0) wredf[wid] = mx;
  __syncthreads();
  if (n == 0) {
    float bmx = fmaxf(fmaxf(wredf[0], wredf[1]), fmaxf(wredf[2], wredf[3]));
    atomicMax(maxenc, enc_f32(bmx));
  }
}

// One block per (b,m); thread n owns row n: out = (X0 + c*eps*hsum)/max.
__global__ __launch_bounds__(256) void k_final(float* __restrict__ Xio,
                                               const float* __restrict__ eps,
                                               const float* __restrict__ hsum,
                                               const double* __restrict__ sumsq,
                                               const unsigned int* __restrict__ maxenc)
{
  const float c = sqrtf((float)(*sumsq / SIGM_DEN));
  const float inv = 1.0f / dec_f32(*maxenc);
  const int n = threadIdx.x;
  const int bm = blockIdx.x;
  const int m = bm & 255;
  float4* __restrict__ r4 = (float4*)(Xio + (size_t)bm * (Mz * Lz) + n * Lz);
  const float* __restrict__ ep = eps + bm * Wz + n;
  const float hv = c * hsum[(m << 8) + n];

  #pragma unroll
  for (int q = 0; q < 6; ++q) {
    float4 t = r4[q];
    t.x = fmaf(hv, ep[4*q+0], t.x) * inv;
    t.y = fmaf(hv, ep[4*q+1], t.y) * inv;
    t.z = fmaf(hv, ep[4*q+2], t.z) * inv;
    t.w = fmaf(hv, ep[4*q+3], t.w) * inv;
    r4[q] = t;
  }
}

extern "C" void kernel_launch(void* const* d_in, const int* in_sizes, int n_in,
                              void* d_out, int out_size, void* d_ws, size_t ws_size,
                              hipStream_t stream) {
  const float* x   = (const float*)d_in[0];   // (4,256,256,24)
  const float* H   = (const float*)d_in[1];   // (1,256,256,1,22)
  const float* eps = (const float*)d_in[2];   // (4,256,279,1)
  float* out = (float*)d_out;                 // (4,256,256,24)

  double*       sumsq  = (double*)d_ws;
  unsigned int* maxenc = (unsigned int*)((char*)d_ws + 8);
  float*        hsum   = (float*)((char*)d_ws + 16);   // 256KB

  k_init  <<<(Mz * Mz + 255) / 256, 256, 0, stream>>>(H, hsum, sumsq, maxenc);
  k_fwd   <<<NBLK, 256, 0, stream>>>(x, H, out, sumsq);
  k_max   <<<NBLK, 256, 0, stream>>>(out, eps, hsum, sumsq, maxenc);
  k_final <<<NBLK, 256, 0, stream>>>(out, eps, hsum, sumsq, maxenc);
}

// Round 10
// 129.356 us; speedup vs baseline: 1.7416x; 1.0510x over previous
//
#include <hip/hip_runtime.h>
#include <math.h>

namespace {
constexpr int Mz = 256, Lz = 24, Sz = 22, Bz = 4;
constexpr int Wz = Mz + Lz - 1;        // 279
constexpr int ST = 26;                  // Ys float2 stride: 26n mod 32 distinct over n mod 16 -> b64 conflict-free
constexpr int NBLK = Bz * Mz;           // 1024
constexpr int NPASS = 7;                // ceil(279 / 41) pipeline passes per block
constexpr double SIGM_DEN = (double)Mz * (double)Wz * (double)Bz * 1e4;
}

__device__ __forceinline__ unsigned int enc_f32(float f) {
  unsigned int u = __float_as_uint(f);
  return (u & 0x80000000u) ? ~u : (u | 0x80000000u);
}
__device__ __forceinline__ float dec_f32(unsigned int e) {
  unsigned int u = (e & 0x80000000u) ? (e ^ 0x80000000u) : ~e;
  return __uint_as_float(u);
}

// lane j <- lane j+1 (srcLane = laneId+1 = DPP wave_shl:1 = 0x130; cf. AMD
// scan idiom where row_shr:N fetches laneId-N); lane 63 <- 0 via bound_ctrl.
__device__ __forceinline__ float rot_down1(float v) {
  return __int_as_float(
      __builtin_amdgcn_update_dpp(0, __float_as_int(v), 0x130, 0xF, 0xF, true));
}

// Zero reduction scalars; hsum[m*256+n] = sum_s H2[m,n,s].
__global__ __launch_bounds__(256) void k_init(const float* __restrict__ H,
                                              float* __restrict__ hsum,
                                              double* __restrict__ sumsq,
                                              unsigned int* __restrict__ maxenc)
{
  int idx = blockIdx.x * 256 + threadIdx.x;
  if (idx == 0) { *sumsq = 0.0; *maxenc = 0u; }
  if (idx < Mz * Mz) {
    const float* __restrict__ hp = H + (size_t)idx * Sz;
    float a = 0.f;
    #pragma unroll
    for (int s = 0; s < Sz; ++s) a += hp[s];
    hsum[idx] = a;
  }
}

// One block per (b,m). Y-build: wave-systolic rolling accumulator (no LDS reads,
// H/x in registers from global, DPP wave_shl rotate). Ys kept in LDS only for
// the X0 phase (unchanged from the measured round-7 structure, hr from global).
__global__ __launch_bounds__(256, 4) void k_fwd(const float* __restrict__ x,
                                                const float* __restrict__ H,
                                                float* __restrict__ X0,
                                                double* __restrict__ sumsq)
{
  __shared__ __align__(16) float Ys[Wz * ST];   // 29016 B
  __shared__ double wred[4];

  const int tid = threadIdx.x;
  const int j  = tid & 63;      // lane
  const int wv = tid >> 6;      // wave 0..3
  const int b = blockIdx.x >> 8;
  const int m = blockIdx.x & 255;
  const float* __restrict__ xp = x + (size_t)(b * Mz + m) * (Mz * Lz);
  const float* __restrict__ Hp = H + (size_t)m * (Mz * Sz);

  double local = 0.0;

  // ---- Y-build: 7 systolic passes, wave wv takes p = wv and wv+4 ----
  for (int pp = 0; pp < 2; ++pp) {
    const int p = wv + 4 * pp;
    if (p >= NPASS) break;                 // wave-uniform
    const int W0 = 41 * p;
    const int n = W0 - 23 + j;             // lane-owned input row
    const bool valid = (n >= 0) && (n < Mz);

    float hr[Sz], xr[Lz];
    if (valid) {
      const float2* __restrict__ h2 = (const float2*)(Hp + n * Sz);
      #pragma unroll
      for (int k = 0; k < 11; ++k) { const float2 h = h2[k]; hr[2*k] = h.x; hr[2*k+1] = h.y; }
      const float4* __restrict__ x4 = (const float4*)(xp + n * Lz);
      #pragma unroll
      for (int k = 0; k < 6; ++k) {
        const float4 t = x4[k];
        xr[4*k] = t.x; xr[4*k+1] = t.y; xr[4*k+2] = t.z; xr[4*k+3] = t.w;
      }
    } else {
      #pragma unroll
      for (int k = 0; k < Sz; ++k) hr[k] = 0.f;
      #pragma unroll
      for (int k = 0; k < Lz; ++k) xr[k] = 0.f;
    }

    float acc[Sz];
    #pragma unroll
    for (int s = 0; s < Sz; ++s) acc[s] = 0.f;

    // invariant: entering step i, lane j's acc = partial Y[n_j + i] (terms i' < i)
    #pragma unroll
    for (int i = 0; i < Lz; ++i) {
      #pragma unroll
      for (int s = 0; s < Sz; ++s) acc[s] = fmaf(hr[s], xr[i], acc[s]);
      if (i < Lz - 1) {
        #pragma unroll
        for (int s = 0; s < Sz; ++s) acc[s] = rot_down1(acc[s]);
      }
    }

    // lanes 0..40 hold complete Y[W0+j]
    const int w = W0 + j;
    if (j <= 40 && w < Wz) {
      float2* __restrict__ yrow = (float2*)&Ys[w * ST];
      #pragma unroll
      for (int k = 0; k < 11; ++k) {
        yrow[k] = make_float2(acc[2*k], acc[2*k+1]);
        local += (double)acc[2*k] * acc[2*k] + (double)acc[2*k+1] * acc[2*k+1];
      }
    }
  }

  // ---- block-reduce sumsq (syncthreads also publishes Ys) ----
  for (int off = 32; off > 0; off >>= 1) local += __shfl_down(local, off, 64);
  const int lane = tid & 63, wid = tid >> 6;
  if (lane == 0) wred[wid] = local;
  __syncthreads();
  if (tid == 0) atomicAdd(sumsq, wred[0] + wred[1] + wred[2] + wred[3]);

  // ---- X0[n,l] = sum_s Ys[n+l][s]*Hs[n][s]; thread owns row n, H[n] regs from global ----
  {
    const int n = tid;
    float hr[Sz];
    {
      const float2* __restrict__ h2 = (const float2*)(Hp + n * Sz);
      #pragma unroll
      for (int k = 0; k < 11; ++k) { const float2 h = h2[k]; hr[2*k] = h.x; hr[2*k+1] = h.y; }
    }
    float4* __restrict__ Xp4 =
        (float4*)(X0 + (size_t)(b * Mz + m) * (Mz * Lz) + n * Lz);
    #pragma unroll
    for (int q = 0; q < 6; ++q) {
      float o[4];
      #pragma unroll
      for (int jj = 0; jj < 4; ++jj) {
        const int l = 4 * q + jj;
        const float2* __restrict__ yr = (const float2*)&Ys[(n + l) * ST];
        float a0 = 0.f, a1 = 0.f;
        #pragma unroll
        for (int k = 0; k < 11; ++k) {
          const float2 y = yr[k];
          a0 = fmaf(y.x, hr[2*k],   a0);
          a1 = fmaf(y.y, hr[2*k+1], a1);
        }
        o[jj] = a0 + a1;
      }
      Xp4[q] = make_float4(o[0], o[1], o[2], o[3]);
    }
  }
}

// One block per (b,m); thread n owns row n: max of X0 + c*eps*hsum.
__global__ __launch_bounds__(256) void k_max(const float* __restrict__ X0,
                                             const float* __restrict__ eps,
                                             const float* __restrict__ hsum,
                                             const double* __restrict__ sumsq,
                                             unsigned int* __restrict__ maxenc)
{
  const float c = sqrtf((float)(*sumsq / SIGM_DEN));
  const int n = threadIdx.x;
  const int bm = blockIdx.x;
  const int m = bm & 255;
  const float4* __restrict__ r4 = (const float4*)(X0 + (size_t)bm * (Mz * Lz) + n * Lz);
  const float* __restrict__ ep = eps + bm * Wz + n;
  const float hv = c * hsum[(m << 8) + n];

  float mx = -3.4e38f;
  #pragma unroll
  for (int q = 0; q < 6; ++q) {
    float4 t = r4[q];
    mx = fmaxf(mx, fmaf(hv, ep[4*q+0], t.x));
    mx = fmaxf(mx, fmaf(hv, ep[4*q+1], t.y));
    mx = fmaxf(mx, fmaf(hv, ep[4*q+2], t.z));
    mx = fmaxf(mx, fmaf(hv, ep[4*q+3], t.w));
  }
  for (int off = 32; off > 0; off >>= 1) mx = fmaxf(mx, __shfl_down(mx, off, 64));
  __shared__ float wredf[4];
  const int lane = n & 63, wid = n >> 6;
  if (lane == 0) wredf[wid] = mx;
  __syncthreads();
  if (n == 0) {
    float bmx = fmaxf(fmaxf(wredf[0], wredf[1]), fmaxf(wredf[2], wredf[3]));
    atomicMax(maxenc, enc_f32(bmx));
  }
}

// One block per (b,m); thread n owns row n: out = (X0 + c*eps*hsum)/max.
__global__ __launch_bounds__(256) void k_final(float* __restrict__ Xio,
                                               const float* __restrict__ eps,
                                               const float* __restrict__ hsum,
                                               const double* __restrict__ sumsq,
                                               const unsigned int* __restrict__ maxenc)
{
  const float c = sqrtf((float)(*sumsq / SIGM_DEN));
  const float inv = 1.0f / dec_f32(*maxenc);
  const int n = threadIdx.x;
  const int bm = blockIdx.x;
  const int m = bm & 255;
  float4* __restrict__ r4 = (float4*)(Xio + (size_t)bm * (Mz * Lz) + n * Lz);
  const float* __restrict__ ep = eps + bm * Wz + n;
  const float hv = c * hsum[(m << 8) + n];

  #pragma unroll
  for (int q = 0; q < 6; ++q) {
    float4 t = r4[q];
    t.x = fmaf(hv, ep[4*q+0], t.x) * inv;
    t.y = fmaf(hv, ep[4*q+1], t.y) * inv;
    t.z = fmaf(hv, ep[4*q+2], t.z) * inv;
    t.w = fmaf(hv, ep[4*q+3], t.w) * inv;
    r4[q] = t;
  }
}

extern "C" void kernel_launch(void* const* d_in, const int* in_sizes, int n_in,
                              void* d_out, int out_size, void* d_ws, size_t ws_size,
                              hipStream_t stream) {
  const float* x   = (const float*)d_in[0];   // (4,256,256,24)
  const float* H   = (const float*)d_in[1];   // (1,256,256,1,22)
  const float* eps = (const float*)d_in[2];   // (4,256,279,1)
  float* out = (float*)d_out;                 // (4,256,256,24)

  double*       sumsq  = (double*)d_ws;
  unsigned int* maxenc = (unsigned int*)((char*)d_ws + 8);
  float*        hsum   = (float*)((char*)d_ws + 16);   // 256KB

  k_init  <<<(Mz * Mz + 255) / 256, 256, 0, stream>>>(H, hsum, sumsq, maxenc);
  k_fwd   <<<NBLK, 256, 0, stream>>>(x, H, out, sumsq);
  k_max   <<<NBLK, 256, 0, stream>>>(out, eps, hsum, sumsq, maxenc);
  k_final <<<NBLK, 256, 0, stream>>>(out, eps, hsum, sumsq, maxenc);
}

// Round 11
// 124.286 us; speedup vs baseline: 1.8126x; 1.0408x over previous
//
#include <hip/hip_runtime.h>
#include <math.h>

namespace {
constexpr int Mz = 256, Lz = 24, Sz = 22, Bz = 4;
constexpr int Wz = Mz + Lz - 1;        // 279
constexpr int ST = 26;                  // Ys float2 stride: 26n mod 32 distinct over n mod 16 -> b64 conflict-free
constexpr int NBLK = Bz * Mz;           // 1024
constexpr int NPASS = 7;                // ceil(279 / 41) pipeline passes per block
constexpr double SIGM_DEN = (double)Mz * (double)Wz * (double)Bz * 1e4;
}

__device__ __forceinline__ unsigned int enc_f32(float f) {
  unsigned int u = __float_as_uint(f);
  return (u & 0x80000000u) ? ~u : (u | 0x80000000u);
}
__device__ __forceinline__ float dec_f32(unsigned int e) {
  unsigned int u = (e & 0x80000000u) ? (e ^ 0x80000000u) : ~e;
  return __uint_as_float(u);
}

// lane j <- lane j+1 (srcLane = laneId+1 = DPP wave_shl:1 = 0x130); lane 63 <- 0.
__device__ __forceinline__ float rot_down1(float v) {
  return __int_as_float(
      __builtin_amdgcn_update_dpp(0, __float_as_int(v), 0x130, 0xF, 0xF, true));
}

// One block per (b,m). Y-build: wave-systolic rolling accumulator (no LDS reads,
// H/x in registers from global, DPP wave_shl rotate). Ys in LDS for the X0 phase.
// b==0 blocks also emit hsum[m*256+n] = sum_s H2[m,n,s] (hr already in regs).
__global__ __launch_bounds__(256, 4) void k_fwd(const float* __restrict__ x,
                                                const float* __restrict__ H,
                                                float* __restrict__ X0,
                                                double* __restrict__ sumsq,
                                                float* __restrict__ hsum)
{
  __shared__ __align__(16) float Ys[Wz * ST];   // 29016 B
  __shared__ double wred[4];

  const int tid = threadIdx.x;
  const int j  = tid & 63;      // lane
  const int wv = tid >> 6;      // wave 0..3
  const int b = blockIdx.x >> 8;
  const int m = blockIdx.x & 255;
  const float* __restrict__ xp = x + (size_t)(b * Mz + m) * (Mz * Lz);
  const float* __restrict__ Hp = H + (size_t)m * (Mz * Sz);

  double local = 0.0;

  // ---- Y-build: 7 systolic passes, wave wv takes p = wv and wv+4 ----
  for (int pp = 0; pp < 2; ++pp) {
    const int p = wv + 4 * pp;
    if (p >= NPASS) break;                 // wave-uniform
    const int W0 = 41 * p;
    const int n = W0 - 23 + j;             // lane-owned input row
    const bool valid = (n >= 0) && (n < Mz);

    float hr[Sz], xr[Lz];
    if (valid) {
      const float2* __restrict__ h2 = (const float2*)(Hp + n * Sz);
      #pragma unroll
      for (int k = 0; k < 11; ++k) { const float2 h = h2[k]; hr[2*k] = h.x; hr[2*k+1] = h.y; }
      const float4* __restrict__ x4 = (const float4*)(xp + n * Lz);
      #pragma unroll
      for (int k = 0; k < 6; ++k) {
        const float4 t = x4[k];
        xr[4*k] = t.x; xr[4*k+1] = t.y; xr[4*k+2] = t.z; xr[4*k+3] = t.w;
      }
    } else {
      #pragma unroll
      for (int k = 0; k < Sz; ++k) hr[k] = 0.f;
      #pragma unroll
      for (int k = 0; k < Lz; ++k) xr[k] = 0.f;
    }

    float acc[Sz];
    #pragma unroll
    for (int s = 0; s < Sz; ++s) acc[s] = 0.f;

    // invariant: entering step i, lane j's acc = partial Y[n_j + i] (terms i' < i)
    #pragma unroll
    for (int i = 0; i < Lz; ++i) {
      #pragma unroll
      for (int s = 0; s < Sz; ++s) acc[s] = fmaf(hr[s], xr[i], acc[s]);
      if (i < Lz - 1) {
        #pragma unroll
        for (int s = 0; s < Sz; ++s) acc[s] = rot_down1(acc[s]);
      }
    }

    // lanes 0..40 hold complete Y[W0+j]
    const int w = W0 + j;
    if (j <= 40 && w < Wz) {
      float2* __restrict__ yrow = (float2*)&Ys[w * ST];
      #pragma unroll
      for (int k = 0; k < 11; ++k) {
        yrow[k] = make_float2(acc[2*k], acc[2*k+1]);
        local += (double)acc[2*k] * acc[2*k] + (double)acc[2*k+1] * acc[2*k+1];
      }
    }
  }

  // ---- block-reduce sumsq (syncthreads also publishes Ys) ----
  for (int off = 32; off > 0; off >>= 1) local += __shfl_down(local, off, 64);
  const int lane = tid & 63, wid = tid >> 6;
  if (lane == 0) wred[wid] = local;
  __syncthreads();
  if (tid == 0) atomicAdd(sumsq, wred[0] + wred[1] + wred[2] + wred[3]);

  // ---- X0[n,l] = sum_s Ys[n+l][s]*H[n][s]; thread owns row n, H[n] regs from global ----
  {
    const int n = tid;
    float hr[Sz];
    {
      const float2* __restrict__ h2 = (const float2*)(Hp + n * Sz);
      #pragma unroll
      for (int k = 0; k < 11; ++k) { const float2 h = h2[k]; hr[2*k] = h.x; hr[2*k+1] = h.y; }
    }
    if (b == 0) {               // fold k_init's hsum into the slab that owns m
      float a = 0.f;
      #pragma unroll
      for (int s = 0; s < Sz; ++s) a += hr[s];
      hsum[(m << 8) + n] = a;   // coalesced across tid
    }
    float4* __restrict__ Xp4 =
        (float4*)(X0 + (size_t)(b * Mz + m) * (Mz * Lz) + n * Lz);
    #pragma unroll
    for (int q = 0; q < 6; ++q) {
      float o[4];
      #pragma unroll
      for (int jj = 0; jj < 4; ++jj) {
        const int l = 4 * q + jj;
        const float2* __restrict__ yr = (const float2*)&Ys[(n + l) * ST];
        float a0 = 0.f, a1 = 0.f;
        #pragma unroll
        for (int k = 0; k < 11; ++k) {
          const float2 y = yr[k];
          a0 = fmaf(y.x, hr[2*k],   a0);
          a1 = fmaf(y.y, hr[2*k+1], a1);
        }
        o[jj] = a0 + a1;
      }
      Xp4[q] = make_float4(o[0], o[1], o[2], o[3]);
    }
  }
}

// One block per (b,m); COALESCED flat float4 scan: lane-consecutive idx4,
// n = idx4/6 (magic-mul), l0 = 4*(idx4%6). Max of X0 + c*eps*hsum.
__global__ __launch_bounds__(256) void k_max(const float* __restrict__ X0,
                                             const float* __restrict__ eps,
                                             const float* __restrict__ hsum,
                                             const double* __restrict__ sumsq,
                                             unsigned int* __restrict__ maxenc)
{
  const float c = sqrtf((float)(*sumsq / SIGM_DEN));
  const int tid = threadIdx.x;
  const int bm = blockIdx.x;
  const int m = bm & 255;
  const float4* __restrict__ slab = (const float4*)(X0 + (size_t)bm * (Mz * Lz));
  const float* __restrict__ ep = eps + bm * Wz;
  const float* __restrict__ hs = hsum + (m << 8);

  float mx = -3.4e38f;
  #pragma unroll
  for (int q = 0; q < 6; ++q) {
    const int idx4 = q * 256 + tid;
    const int n = idx4 / 6;
    const int l0 = 4 * (idx4 - 6 * n);
    const float4 t = slab[idx4];
    const float hv = c * hs[n];
    const float* __restrict__ e4 = ep + n + l0;
    mx = fmaxf(mx, fmaf(hv, e4[0], t.x));
    mx = fmaxf(mx, fmaf(hv, e4[1], t.y));
    mx = fmaxf(mx, fmaf(hv, e4[2], t.z));
    mx = fmaxf(mx, fmaf(hv, e4[3], t.w));
  }
  for (int off = 32; off > 0; off >>= 1) mx = fmaxf(mx, __shfl_down(mx, off, 64));
  __shared__ float wredf[4];
  const int lane = tid & 63, wid = tid >> 6;
  if (lane == 0) wredf[wid] = mx;
  __syncthreads();
  if (tid == 0) {
    float bmx = fmaxf(fmaxf(wredf[0], wredf[1]), fmaxf(wredf[2], wredf[3]));
    atomicMax(maxenc, enc_f32(bmx));
  }
}

// Same coalesced pattern: out = (X0 + c*eps*hsum)/max, in place.
__global__ __launch_bounds__(256) void k_final(float* __restrict__ Xio,
                                               const float* __restrict__ eps,
                                               const float* __restrict__ hsum,
                                               const double* __restrict__ sumsq,
                                               const unsigned int* __restrict__ maxenc)
{
  const float c = sqrtf((float)(*sumsq / SIGM_DEN));
  const float inv = 1.0f / dec_f32(*maxenc);
  const int tid = threadIdx.x;
  const int bm = blockIdx.x;
  const int m = bm & 255;
  float4* __restrict__ slab = (float4*)(Xio + (size_t)bm * (Mz * Lz));
  const float* __restrict__ ep = eps + bm * Wz;
  const float* __restrict__ hs = hsum + (m << 8);

  #pragma unroll
  for (int q = 0; q < 6; ++q) {
    const int idx4 = q * 256 + tid;
    const int n = idx4 / 6;
    const int l0 = 4 * (idx4 - 6 * n);
    float4 t = slab[idx4];
    const float hv = c * hs[n];
    const float* __restrict__ e4 = ep + n + l0;
    t.x = fmaf(hv, e4[0], t.x) * inv;
    t.y = fmaf(hv, e4[1], t.y) * inv;
    t.z = fmaf(hv, e4[2], t.z) * inv;
    t.w = fmaf(hv, e4[3], t.w) * inv;
    slab[idx4] = t;
  }
}

extern "C" void kernel_launch(void* const* d_in, const int* in_sizes, int n_in,
                              void* d_out, int out_size, void* d_ws, size_t ws_size,
                              hipStream_t stream) {
  const float* x   = (const float*)d_in[0];   // (4,256,256,24)
  const float* H   = (const float*)d_in[1];   // (1,256,256,1,22)
  const float* eps = (const float*)d_in[2];   // (4,256,279,1)
  float* out = (float*)d_out;                 // (4,256,256,24)

  double*       sumsq  = (double*)d_ws;
  unsigned int* maxenc = (unsigned int*)((char*)d_ws + 8);
  float*        hsum   = (float*)((char*)d_ws + 16);   // 256KB

  hipMemsetAsync(d_ws, 0, 16, stream);   // zero sumsq + maxenc (capture-legal)
  k_fwd   <<<NBLK, 256, 0, stream>>>(x, H, out, sumsq, hsum);
  k_max   <<<NBLK, 256, 0, stream>>>(out, eps, hsum, sumsq, maxenc);
  k_final <<<NBLK, 256, 0, stream>>>(out, eps, hsum, sumsq, maxenc);
}